// Round 1
// baseline (2853.235 us; speedup 1.0000x reference)
//
#include <hip/hip_runtime.h>

#define HS    128
#define INP   23
#define NF    24      // features incl. time
#define NGATE 512     // 4*HS
#define TLEN  1024
#define BATCH 512

__device__ __forceinline__ float fexp(float x) {
    return __builtin_amdgcn_exp2f(x * 1.4426950408889634f);
}
__device__ __forceinline__ float fsigmoid(float x) {
    return __builtin_amdgcn_rcpf(1.0f + fexp(-x));
}
__device__ __forceinline__ float ftanh(float x) {
    // tanh(x) = 2*sigmoid(2x) - 1 ; saturates correctly for |x| large
    return 2.0f * fsigmoid(2.0f * x) - 1.0f;
}

__global__ __launch_bounds__(512, 2)
void lstm_fused_kernel(const float* __restrict__ points,
                       const float* __restrict__ times,
                       const float* __restrict__ W,
                       const float* __restrict__ U,
                       const float* __restrict__ bias,
                       const float* __restrict__ Wc,
                       const float* __restrict__ bc,
                       float* __restrict__ out)
{
    const int b = blockIdx.x;     // batch row
    const int g = threadIdx.x;    // gate column 0..511

    __shared__ __align__(16) float h_lds[HS];
    __shared__ __align__(16) float gates[NGATE];
    __shared__ __align__(16) float xbuf[2][32];   // 24 used, padded
    __shared__ float opart[2][2];

    // ---- preload weights into registers (coalesced across threads) ----
    float Ucol[HS];
    #pragma unroll
    for (int k = 0; k < HS; ++k) Ucol[k] = U[k * NGATE + g];

    float Wcol[NF];
    #pragma unroll
    for (int f = 0; f < NF; ++f) Wcol[f] = W[f * NGATE + g];

    const float bcol = bias[g];
    const float bc0 = bc[0], bc1 = bc[1];

    float wc0 = 0.0f, wc1 = 0.0f, c = 0.0f;
    if (g < HS) {
        wc0 = Wc[2 * g];
        wc1 = Wc[2 * g + 1];
        h_lds[g] = 0.0f;      // h0 = 0
    }

    const float* px = points + (size_t)b * TLEN * INP;
    const float* pt = times  + (size_t)b * TLEN;
    float2* pout = (float2*)out + (size_t)b * TLEN;

    // stage x for t = 0
    if (g < INP)  xbuf[0][g]   = px[g];
    if (g == INP) xbuf[0][INP] = pt[0];
    __syncthreads();

    for (int t = 0; t < TLEN; ++t) {
        const int cur = t & 1, nxt = cur ^ 1;

        // prefetch x for step t+1 (consumed after 2 barriers -> latency hidden)
        if (t + 1 < TLEN) {
            if (g < INP)  xbuf[nxt][g]   = px[(t + 1) * INP + g];
            if (g == INP) xbuf[nxt][INP] = pt[t + 1];
        }

        // ---- gate pre-activation: bias + x.W + h.U (4 indep FMA chains) ----
        float a0 = bcol, a1 = 0.0f, a2 = 0.0f, a3 = 0.0f;
        const float4* h4 = (const float4*)h_lds;
        #pragma unroll
        for (int kk = 0; kk < HS / 4; ++kk) {
            float4 hv = h4[kk];
            a0 = fmaf(hv.x, Ucol[4 * kk + 0], a0);
            a1 = fmaf(hv.y, Ucol[4 * kk + 1], a1);
            a2 = fmaf(hv.z, Ucol[4 * kk + 2], a2);
            a3 = fmaf(hv.w, Ucol[4 * kk + 3], a3);
        }
        const float4* x4 = (const float4*)xbuf[cur];
        #pragma unroll
        for (int ff = 0; ff < NF / 4; ++ff) {
            float4 xv = x4[ff];
            a0 = fmaf(xv.x, Wcol[4 * ff + 0], a0);
            a1 = fmaf(xv.y, Wcol[4 * ff + 1], a1);
            a2 = fmaf(xv.z, Wcol[4 * ff + 2], a2);
            a3 = fmaf(xv.w, Wcol[4 * ff + 3], a3);
        }
        const float pre = (a0 + a1) + (a2 + a3);

        // sigmoid for i,f,o ; tanh for g-gate (columns [256,384))
        const float act = (g >= 2 * HS && g < 3 * HS) ? ftanh(pre) : fsigmoid(pre);
        gates[g] = act;
        __syncthreads();   // barrier A: gates published

        if (g < HS) {      // waves 0,1 exactly -> no intra-wave divergence
            const float ig = gates[g];
            const float fg = gates[HS + g];
            const float gg = gates[2 * HS + g];
            const float og = gates[3 * HS + g];
            c = fg * c + ig * gg;
            const float h = og * ftanh(c);
            h_lds[g] = h;

            // output projection partials: h . Wc (2 cols), 64-lane reduce
            float p0 = h * wc0, p1 = h * wc1;
            #pragma unroll
            for (int off = 32; off; off >>= 1) {
                p0 += __shfl_down(p0, off);
                p1 += __shfl_down(p1, off);
            }
            if ((g & 63) == 0) {
                opart[g >> 6][0] = p0;
                opart[g >> 6][1] = p1;
            }
        }
        __syncthreads();   // barrier B: h (and opart) published

        if (g == 0) {
            const float o0 = fsigmoid(opart[0][0] + opart[1][0] + bc0);
            const float o1 = fsigmoid(opart[0][1] + opart[1][1] + bc1);
            pout[t] = make_float2(o0, o1);
        }
    }
}

extern "C" void kernel_launch(void* const* d_in, const int* in_sizes, int n_in,
                              void* d_out, int out_size, void* d_ws, size_t ws_size,
                              hipStream_t stream) {
    const float* points = (const float*)d_in[0];
    const float* times  = (const float*)d_in[1];
    const float* W      = (const float*)d_in[2];
    const float* U      = (const float*)d_in[3];
    const float* bias   = (const float*)d_in[4];
    const float* Wc     = (const float*)d_in[5];
    const float* bc     = (const float*)d_in[6];
    float* out = (float*)d_out;

    lstm_fused_kernel<<<dim3(BATCH), dim3(NGATE), 0, stream>>>(
        points, times, W, U, bias, Wc, bc, out);
}